// Round 6
// baseline (235.770 us; speedup 1.0000x reference)
//
#include <hip/hip_runtime.h>

// Problem constants (from reference):
//   x: [B=32, C=1, F=257, T=4096] float32 log-magnitude spectrogram
//   SHIFT_BINS = 20.0 / (16000/512) = 0.64  -> f_low = f, f_high = f+1
//   out[b,f,t] = log10((1-a)*10^x[b,f,t] + a*10^x[b,f+1,t] + 1e-8), f < 256
//   out[b,256,t] = log10(1e-8)   (valid mask false at the top bin)
//
// Round 6: force memory-level parallelism with inline-asm loads.
// R0-R5 post-mortem: VGPR_Count stayed 24 through every "staging" attempt —
// hipcc sank the loads to their uses each time (even past sched_barrier(0)),
// so only ~2 loads/wave were ever in flight and the kernel stayed
// latency-bound at ~82 µs / ~3 TB/s while the write-only fill streams 6.7.
// asm volatile global_load_dwordx4 cannot be sunk: 8 loads (8 KB/wave) are
// issued back-to-back, compute runs behind counted s_waitcnt vmcnt(6/4/2/0)
// (+ sched_barrier(0) per rule #18 so VALU can't hoist past the wait).
// Stores are grouped at the end so the counted waits see only loads.
#define B_DIM 32
#define F_DIM 257
#define T_DIM 4096
#define EPS_F 1e-8f

#define LOG2_10  3.32192809488736234787f
#define LOG10_2  0.30102999566398119521f

#define NBLK      (B_DIM * F_DIM)     // 8224
#define XCD_CHUNK (NBLK / 8)          // 1028, exact -> bijective swizzle
#define ROWV      (T_DIM / 4)         // 1024 f32x4 per row

typedef float f32x4 __attribute__((ext_vector_type(4)));

// Un-sinkable 16B load: compiler must keep dst live from issue to use.
#define GLOAD(dst, ptr) \
    asm volatile("global_load_dwordx4 %0, %1, off" : "=v"(dst) : "v"(ptr))

// Counted wait + scheduler fence (rule #18: without the fence, register-only
// VALU gets hoisted above an inline-asm s_waitcnt despite the clobber).
#define VWAIT(n) do { \
    asm volatile("s_waitcnt vmcnt(" #n ")" ::: "memory"); \
    __builtin_amdgcn_sched_barrier(0); } while (0)

__device__ __forceinline__ float pow10_fast(float v) {
    // 10^v = 2^(v * log2(10)); v_exp_f32 is ~1 ulp — far under the absmax threshold
    return __builtin_amdgcn_exp2f(v * LOG2_10);
}
__device__ __forceinline__ float log10_fast(float v) {
    return __builtin_amdgcn_logf(v) * LOG10_2;  // v_log_f32 is log2
}

__device__ __forceinline__ f32x4 interp4(f32x4 a, f32x4 b, float alpha, float beta) {
    f32x4 r;
    r.x = log10_fast(beta * pow10_fast(a.x) + alpha * pow10_fast(b.x) + EPS_F);
    r.y = log10_fast(beta * pow10_fast(a.y) + alpha * pow10_fast(b.y) + EPS_F);
    r.z = log10_fast(beta * pow10_fast(a.z) + alpha * pow10_fast(b.z) + EPS_F);
    r.w = log10_fast(beta * pow10_fast(a.w) + alpha * pow10_fast(b.w) + EPS_F);
    return r;
}

__global__ __launch_bounds__(256) void freq_shift_kernel(
        const float* __restrict__ x, float* __restrict__ out) {
    // XCD-chunked bijective swizzle (kept from R5: halves HBM fetch via L2
    // hits on the shared boundary row -> lower average read latency).
    const int bid = blockIdx.x;
    const int bf  = (bid & 7) * XCD_CHUNK + (bid >> 3);

    const int f  = bf % F_DIM;
    const long long base = (long long)bf * T_DIM;
    const int tid = threadIdx.x;

    f32x4* __restrict__ orow = (f32x4*)(out + base);

    if (f == F_DIM - 1) {
        // invalid top bin: log10(0 + 1e-8); block-uniform branch, no divergence
        const float cv = log10_fast(EPS_F);
        f32x4 v; v.x = cv; v.y = cv; v.z = cv; v.w = cv;
#pragma unroll
        for (int i = 0; i < T_DIM / 4 / 256; ++i)
            __builtin_nontemporal_store(v, orow + i * 256 + tid);
        return;
    }

    const f32x4* __restrict__ row0 = (const f32x4*)(x + base) + tid;
    const f32x4* __restrict__ row1 = row0 + ROWV;

    // Reproduce reference fp32 alpha: target = fl(f + 0.64f); alpha = target - f
    // (exact subtraction by Sterbenz; matches jnp float32 weak-typed arithmetic)
    const float ff    = (float)f;
    const float alpha = (ff + 0.64f) - ff;
    const float beta  = 1.0f - alpha;

    // Issue ALL 8 loads back-to-back, oldest-first in consumption order.
    f32x4 va0, vb0, va1, vb1, va2, vb2, va3, vb3;
    GLOAD(va0, row0);        GLOAD(vb0, row1);
    GLOAD(va1, row0 + 256);  GLOAD(vb1, row1 + 256);
    GLOAD(va2, row0 + 512);  GLOAD(vb2, row1 + 512);
    GLOAD(va3, row0 + 768);  GLOAD(vb3, row1 + 768);

    // Compute each pair as soon as ITS loads retire; 6/4/2 younger loads stay
    // in flight under the transcendental chains.
    f32x4 r0, r1, r2, r3;
    VWAIT(6);  r0 = interp4(va0, vb0, alpha, beta);
    VWAIT(4);  r1 = interp4(va1, vb1, alpha, beta);
    VWAIT(2);  r2 = interp4(va2, vb2, alpha, beta);
    VWAIT(0);  r3 = interp4(va3, vb3, alpha, beta);

    // out is write-once, never re-read: nontemporal stores keep cache lines
    // free for the shared boundary-row reads.
    __builtin_nontemporal_store(r0, orow + tid);
    __builtin_nontemporal_store(r1, orow + 256 + tid);
    __builtin_nontemporal_store(r2, orow + 512 + tid);
    __builtin_nontemporal_store(r3, orow + 768 + tid);
}

extern "C" void kernel_launch(void* const* d_in, const int* in_sizes, int n_in,
                              void* d_out, int out_size, void* d_ws, size_t ws_size,
                              hipStream_t stream) {
    const float* x = (const float*)d_in[0];
    float* out = (float*)d_out;
    // grid: one block per (b,f) row; 32*257 = 8224 blocks, 256 threads,
    // 4 float4 iterations per thread covering T=4096
    dim3 grid(NBLK);
    dim3 block(256);
    freq_shift_kernel<<<grid, block, 0, stream>>>(x, out);
}